// Round 1
// baseline (415.772 us; speedup 1.0000x reference)
//
#include <hip/hip_runtime.h>

// out[b, f] = 1.0f if (medians[f] > 0) && (x[b, f] >= medians[f]) else 0.0f
// x: (16384, 4096) fp32, medians: (4096,) fp32, out: (16384, 4096) fp32.
// Memory-bound: 512 MiB HBM traffic, floor ~85 us at 6.3 TB/s.
// float4 per thread (16 B/lane coalescing sweet spot). Row length 4096 floats
// = 1024 float4, so medians float4 index = flat4 & 1023 (L1-cached broadcast).

#define F4_PER_ROW 1024  // 4096 / 4

__global__ __launch_bounds__(256) void binarize_kernel(
    const float4* __restrict__ x4,
    const float4* __restrict__ med4,
    float4* __restrict__ out4,
    int n4) {
    int idx = blockIdx.x * blockDim.x + threadIdx.x;
    if (idx >= n4) return;

    float4 xv = x4[idx];
    float4 mv = med4[idx & (F4_PER_ROW - 1)];

    float4 o;
    o.x = (mv.x > 0.0f && xv.x >= mv.x) ? 1.0f : 0.0f;
    o.y = (mv.y > 0.0f && xv.y >= mv.y) ? 1.0f : 0.0f;
    o.z = (mv.z > 0.0f && xv.z >= mv.z) ? 1.0f : 0.0f;
    o.w = (mv.w > 0.0f && xv.w >= mv.w) ? 1.0f : 0.0f;

    out4[idx] = o;
}

extern "C" void kernel_launch(void* const* d_in, const int* in_sizes, int n_in,
                              void* d_out, int out_size, void* d_ws, size_t ws_size,
                              hipStream_t stream) {
    const float4* x4   = (const float4*)d_in[0];
    const float4* med4 = (const float4*)d_in[1];
    float4* out4       = (float4*)d_out;

    int n4 = out_size / 4;  // 16384*4096/4 = 16,777,216
    int block = 256;
    int grid = (n4 + block - 1) / block;  // 65536

    binarize_kernel<<<grid, block, 0, stream>>>(x4, med4, out4, n4);
}

// Round 3
// 413.520 us; speedup vs baseline: 1.0054x; 1.0054x over previous
//
#include <hip/hip_runtime.h>

// out[b, f] = 1.0f if (medians[f] > 0) && (x[b, f] >= medians[f]) else 0.0f
// x: (16384, 4096) fp32, medians: (4096,) fp32, out: (16384, 4096) fp32.
// Memory-bound: 536 MB HBM traffic, floor ~84 us at 6.4 TB/s (harness fills
// demonstrate 6.4 TB/s achievable on this chip/stream).
//
// R2 = R1 with compile fix: __builtin_nontemporal_* requires a clang native
// vector type, not HIP's struct float4 — use ext_vector_type(4).

typedef float vfloat4 __attribute__((ext_vector_type(4)));

#define F4_PER_ROW 1024  // 4096 / 4

__global__ __launch_bounds__(256) void binarize_kernel(
    const vfloat4* __restrict__ x4,
    const vfloat4* __restrict__ med4,
    vfloat4* __restrict__ out4) {
    int idx = blockIdx.x * 256 + threadIdx.x;

    vfloat4 xv = __builtin_nontemporal_load(&x4[idx]);
    vfloat4 mv = med4[idx & (F4_PER_ROW - 1)];  // cached: 16 KiB, heavy reuse

    vfloat4 o;
    o.x = (mv.x > 0.0f && xv.x >= mv.x) ? 1.0f : 0.0f;
    o.y = (mv.y > 0.0f && xv.y >= mv.y) ? 1.0f : 0.0f;
    o.z = (mv.z > 0.0f && xv.z >= mv.z) ? 1.0f : 0.0f;
    o.w = (mv.w > 0.0f && xv.w >= mv.w) ? 1.0f : 0.0f;

    __builtin_nontemporal_store(o, &out4[idx]);
}

extern "C" void kernel_launch(void* const* d_in, const int* in_sizes, int n_in,
                              void* d_out, int out_size, void* d_ws, size_t ws_size,
                              hipStream_t stream) {
    const vfloat4* x4   = (const vfloat4*)d_in[0];
    const vfloat4* med4 = (const vfloat4*)d_in[1];
    vfloat4* out4       = (vfloat4*)d_out;

    int n4 = out_size / 4;        // 16,777,216
    int block = 256;
    int grid = n4 / block;        // 65536, exact fit (16384*4096 % 1024 == 0)

    binarize_kernel<<<grid, block, 0, stream>>>(x4, med4, out4);
}